// Round 1
// baseline (331.627 us; speedup 1.0000x reference)
//
#include <hip/hip_runtime.h>
#include <hip/hip_bf16.h>

#define BB 8
#define SS 1024
#define EE 768
#define HH 12
#define DD 64
#define NT (BB*SS)

typedef __attribute__((ext_vector_type(8))) short bf16x8;
typedef __attribute__((ext_vector_type(4))) float f32x4;

__device__ __forceinline__ ushort f2bf(float f) {
  union { float f; unsigned u; } x; x.f = f;
  unsigned r = x.u + 0x7fffu + ((x.u >> 16) & 1u);
  return (ushort)(r >> 16);
}

// ---------------- weight conversion ----------------
__global__ void cvt_weights(const float* __restrict__ Wq, const float* __restrict__ Wk,
                            const float* __restrict__ Wv, const float* __restrict__ Wo,
                            ushort* __restrict__ Wqb, ushort* __restrict__ Wkb,
                            ushort* __restrict__ Wvb, ushort* __restrict__ Wob) {
  int i = blockIdx.x * blockDim.x + threadIdx.x;
  const int NW = HH*DD*DD;           // 49152
  if (i < NW) { Wqb[i] = f2bf(Wq[i]); Wkb[i] = f2bf(Wk[i]); Wvb[i] = f2bf(Wv[i]); }
  if (i < EE*EE) Wob[i] = f2bf(Wo[i]);
}

// ---------------- QKV projection ----------------
// Q,K out: [B,H,S,D] bf16 (Q pre-scaled by 1/8).  V out: [B,H,D,S] bf16 (transposed).
__global__ __launch_bounds__(256) void proj_qkv(
    const float* __restrict__ q, const float* __restrict__ k, const float* __restrict__ v,
    const ushort* __restrict__ Wqb, const ushort* __restrict__ Wkb, const ushort* __restrict__ Wvb,
    ushort* __restrict__ Qb, ushort* __restrict__ Kb, ushort* __restrict__ Vt) {
  int bid = blockIdx.x;
  int m  = bid / (BB*HH*(SS/64));
  int r  = bid % (BB*HH*(SS/64));
  int bh = r / (SS/64);
  int st = r % (SS/64);
  int b = bh / HH, h = bh % HH;

  const float*  x = (m==0 ? q : (m==1 ? k : v)) + ((size_t)(b*SS + st*64))*EE + h*DD;
  const ushort* W = (m==0 ? Wqb : (m==1 ? Wkb : Wvb)) + h*DD*DD;

  int tid = threadIdx.x;
  int w = tid >> 6, l = tid & 63;
  int lr = l & 15, lg = l >> 4;

  // A fragments: rows w*16+lr, k = ks*32 + lg*8 + j (contiguous fp32 -> bf16)
  bf16x8 a[2];
  const float* xr = x + (size_t)(w*16 + lr)*EE;
#pragma unroll
  for (int ks = 0; ks < 2; ++ks) {
    f32x4 t0 = *(const f32x4*)(xr + ks*32 + lg*8);
    f32x4 t1 = *(const f32x4*)(xr + ks*32 + lg*8 + 4);
    bf16x8 av;
#pragma unroll
    for (int j = 0; j < 4; ++j) { av[j] = (short)f2bf(t0[j]); av[4+j] = (short)f2bf(t1[j]); }
    a[ks] = av;
  }

  f32x4 acc[4] = {};
#pragma unroll
  for (int f = 0; f < 4; ++f) {
    bf16x8 b0 = *(const bf16x8*)(W + (f*16 + lr)*DD + lg*8);
    bf16x8 b1 = *(const bf16x8*)(W + (f*16 + lr)*DD + 32 + lg*8);
    acc[f] = __builtin_amdgcn_mfma_f32_16x16x32_bf16(a[0], b0, acc[f], 0, 0, 0);
    acc[f] = __builtin_amdgcn_mfma_f32_16x16x32_bf16(a[1], b1, acc[f], 0, 0, 0);
  }

  float qscale = (m == 0) ? 0.125f : 1.0f;
#pragma unroll
  for (int f = 0; f < 4; ++f) {
#pragma unroll
    for (int j = 0; j < 4; ++j) {
      int srow = st*64 + w*16 + lg*4 + j;
      int col  = f*16 + lr;
      ushort val = f2bf(acc[f][j] * qscale);
      if (m == 2)      Vt[((size_t)bh*DD + col)*SS + srow] = val;
      else if (m == 0) Qb[((size_t)bh*SS + srow)*DD + col] = val;
      else             Kb[((size_t)bh*SS + srow)*DD + col] = val;
    }
  }
}

// ---------------- flash attention ----------------
// Per block: one (b,h), 64 q-rows (4 waves x 16). Online softmax fp32.
__global__ __launch_bounds__(256) void attn_fwd(
    const ushort* __restrict__ Qb, const ushort* __restrict__ Kb,
    const ushort* __restrict__ Vt, ushort* __restrict__ attn) {
  __shared__ ushort plds[4*16*64];   // 8 KiB, per-wave 2KB regions

  int bid = blockIdx.x;
  int bh = bid / (SS/64);
  int qt = bid % (SS/64);
  int b = bh / HH, h = bh % HH;
  int tid = threadIdx.x, w = tid >> 6, l = tid & 63;
  int lr = l & 15, lg = l >> 4;

  const ushort* Qp = Qb + ((size_t)bh*SS + qt*64 + w*16 + lr)*DD;
  bf16x8 aq[2];
  aq[0] = *(const bf16x8*)(Qp + lg*8);
  aq[1] = *(const bf16x8*)(Qp + 32 + lg*8);

  float m_run[4], l_run[4];
  f32x4 o[4] = {};
#pragma unroll
  for (int j = 0; j < 4; ++j) { m_run[j] = -1e30f; l_run[j] = 0.f; }

  char* myplds = (char*)plds + w*2048;
  const ushort* Kbase = Kb + (size_t)bh*SS*DD;
  const ushort* Vbase = Vt + (size_t)bh*DD*SS;

  for (int kt = 0; kt < SS/64; ++kt) {
    const ushort* Kp = Kbase + (size_t)kt*64*DD;
    f32x4 s[4] = {};
#pragma unroll
    for (int f = 0; f < 4; ++f) {
      bf16x8 bk0 = *(const bf16x8*)(Kp + (f*16 + lr)*DD + lg*8);
      bf16x8 bk1 = *(const bf16x8*)(Kp + (f*16 + lr)*DD + 32 + lg*8);
      s[f] = __builtin_amdgcn_mfma_f32_16x16x32_bf16(aq[0], bk0, s[f], 0, 0, 0);
      s[f] = __builtin_amdgcn_mfma_f32_16x16x32_bf16(aq[1], bk1, s[f], 0, 0, 0);
    }
    // row max across 4 frags + 16-lane butterfly
    float rmax[4];
#pragma unroll
    for (int j = 0; j < 4; ++j)
      rmax[j] = fmaxf(fmaxf(s[0][j], s[1][j]), fmaxf(s[2][j], s[3][j]));
#pragma unroll
    for (int off = 1; off < 16; off <<= 1) {
#pragma unroll
      for (int j = 0; j < 4; ++j) rmax[j] = fmaxf(rmax[j], __shfl_xor(rmax[j], off, 64));
    }
    float p[4][4], rsum[4];
#pragma unroll
    for (int j = 0; j < 4; ++j) {
      float mn = fmaxf(m_run[j], rmax[j]);
      float sc = __expf(m_run[j] - mn);
      m_run[j] = mn;
      l_run[j] *= sc;
#pragma unroll
      for (int f = 0; f < 4; ++f) p[f][j] = __expf(s[f][j] - mn);
      rsum[j] = (p[0][j] + p[1][j]) + (p[2][j] + p[3][j]);
#pragma unroll
      for (int f = 0; f < 4; ++f) o[f][j] *= sc;
    }
#pragma unroll
    for (int off = 1; off < 16; off <<= 1) {
#pragma unroll
      for (int j = 0; j < 4; ++j) rsum[j] += __shfl_xor(rsum[j], off, 64);
    }
#pragma unroll
    for (int j = 0; j < 4; ++j) l_run[j] += rsum[j];

    // P -> LDS (XOR-swizzled rows, wave-private region, no barrier needed)
#pragma unroll
    for (int f = 0; f < 4; ++f) {
#pragma unroll
      for (int j = 0; j < 4; ++j) {
        int rr = lg*4 + j;
        int cc = f*16 + lr;
        unsigned off2 = (unsigned)(rr*128 + cc*2);
        off2 ^= (unsigned)((rr & 7) << 4);
        *(ushort*)(myplds + off2) = f2bf(p[f][j]);
      }
    }
    // P A-fragments back from LDS
    bf16x8 ap[2];
#pragma unroll
    for (int ks = 0; ks < 2; ++ks) {
      unsigned off2 = (unsigned)(lr*128 + ks*64 + lg*16);
      off2 ^= (unsigned)((lr & 7) << 4);
      ap[ks] = *(const bf16x8*)(myplds + off2);
    }
    // PV
    const ushort* Vp = Vbase + kt*64;
#pragma unroll
    for (int f = 0; f < 4; ++f) {
      bf16x8 bv0 = *(const bf16x8*)(Vp + (size_t)(f*16 + lr)*SS + lg*8);
      bf16x8 bv1 = *(const bf16x8*)(Vp + (size_t)(f*16 + lr)*SS + 32 + lg*8);
      o[f] = __builtin_amdgcn_mfma_f32_16x16x32_bf16(ap[0], bv0, o[f], 0, 0, 0);
      o[f] = __builtin_amdgcn_mfma_f32_16x16x32_bf16(ap[1], bv1, o[f], 0, 0, 0);
    }
  }

  // epilogue: normalize, store merged-head attn bf16 [B,S,E]
#pragma unroll
  for (int j = 0; j < 4; ++j) {
    float inv = 1.0f / l_run[j];
    int srow = qt*64 + w*16 + lg*4 + j;
#pragma unroll
    for (int f = 0; f < 4; ++f) {
      int col = h*DD + f*16 + lr;
      attn[((size_t)(b*SS + srow))*EE + col] = f2bf(o[f][j] * inv);
    }
  }
}

// ---------------- output projection ----------------
__global__ __launch_bounds__(256) void out_proj(
    const ushort* __restrict__ attn, const ushort* __restrict__ Wob,
    const float* __restrict__ bo, float* __restrict__ out) {
  int bid = blockIdx.x;
  int mt = bid / (EE/64);
  int nt = bid % (EE/64);
  int tid = threadIdx.x, w = tid >> 6, l = tid & 63;
  int lr = l & 15, lg = l >> 4;

  const ushort* ar = attn + ((size_t)(mt*64 + w*16 + lr))*EE;
  f32x4 acc[4] = {};
  for (int ks = 0; ks < EE/32; ++ks) {
    bf16x8 a = *(const bf16x8*)(ar + ks*32 + lg*8);
#pragma unroll
    for (int f = 0; f < 4; ++f) {
      bf16x8 bb = *(const bf16x8*)(Wob + (size_t)(nt*64 + f*16 + lr)*EE + ks*32 + lg*8);
      acc[f] = __builtin_amdgcn_mfma_f32_16x16x32_bf16(a, bb, acc[f], 0, 0, 0);
    }
  }
#pragma unroll
  for (int f = 0; f < 4; ++f) {
    int col = nt*64 + f*16 + lr;
    float bias = bo[col];
#pragma unroll
    for (int j = 0; j < 4; ++j) {
      int row = mt*64 + w*16 + lg*4 + j;
      out[(size_t)row*EE + col] = acc[f][j] + bias;
    }
  }
}

extern "C" void kernel_launch(void* const* d_in, const int* in_sizes, int n_in,
                              void* d_out, int out_size, void* d_ws, size_t ws_size,
                              hipStream_t stream) {
  (void)in_sizes; (void)n_in; (void)out_size; (void)ws_size;
  const float* q  = (const float*)d_in[0];
  const float* k  = (const float*)d_in[1];
  const float* v  = (const float*)d_in[2];
  const float* Wq = (const float*)d_in[3];
  const float* Wk = (const float*)d_in[4];
  const float* Wv = (const float*)d_in[5];
  const float* Wo = (const float*)d_in[6];
  const float* bo = (const float*)d_in[7];
  float* out = (float*)d_out;

  char* ws = (char*)d_ws;
  const size_t SZ = (size_t)BB*HH*SS*DD*2;     // 12582912 bytes each
  ushort* Qb   = (ushort*)(ws);
  ushort* Kb   = (ushort*)(ws + SZ);
  ushort* Vt   = (ushort*)(ws + 2*SZ);
  ushort* attn = (ushort*)(ws + 3*SZ);
  ushort* Wqb  = (ushort*)(ws + 4*SZ);
  ushort* Wkb  = (ushort*)(ws + 4*SZ +   98304);
  ushort* Wvb  = (ushort*)(ws + 4*SZ + 2*98304);
  ushort* Wob  = (ushort*)(ws + 4*SZ + 3*98304);

  cvt_weights<<<(EE*EE + 255)/256, 256, 0, stream>>>(Wq, Wk, Wv, Wo, Wqb, Wkb, Wvb, Wob);
  proj_qkv<<<3*BB*HH*(SS/64), 256, 0, stream>>>(q, k, v, Wqb, Wkb, Wvb, Qb, Kb, Vt);
  attn_fwd<<<BB*HH*(SS/64), 256, 0, stream>>>(Qb, Kb, Vt, attn);
  out_proj<<<(NT/64)*(EE/64), 256, 0, stream>>>(attn, Wob, bo, out);
}

// Round 2
// 181.641 us; speedup vs baseline: 1.8257x; 1.8257x over previous
//
#include <hip/hip_runtime.h>
#include <hip/hip_bf16.h>

#define BB 8
#define SS 1024
#define EE 768
#define HH 12
#define DD 64
#define NT (BB*SS)

typedef __attribute__((ext_vector_type(8))) short bf16x8;
typedef __attribute__((ext_vector_type(4))) short bf16x4;
typedef __attribute__((ext_vector_type(4))) float f32x4;

__device__ __forceinline__ ushort f2bf(float f) {
  union { float f; unsigned u; } x; x.f = f;
  unsigned r = x.u + 0x7fffu + ((x.u >> 16) & 1u);
  return (ushort)(r >> 16);
}

// pack two floats to bf16 pair (simple round-half-up)
__device__ __forceinline__ unsigned pk2(float a, float b) {
  union { float f; unsigned u; } A, B; A.f = a; B.f = b;
  return ((A.u + 0x8000u) >> 16) | ((B.u + 0x8000u) & 0xffff0000u);
}

__device__ __forceinline__ bf16x8 cat8(bf16x4 a, bf16x4 b) {
  bf16x8 r;
  r[0]=a[0]; r[1]=a[1]; r[2]=a[2]; r[3]=a[3];
  r[4]=b[0]; r[5]=b[1]; r[6]=b[2]; r[7]=b[3];
  return r;
}

__device__ __forceinline__ void gl2lds(const void* g, void* l) {
  __builtin_amdgcn_global_load_lds(
      (const __attribute__((address_space(1))) unsigned int*)g,
      (__attribute__((address_space(3))) unsigned int*)l, 16, 0, 0);
}

// ---------------- weight conversion ----------------
__global__ void cvt_weights(const float* __restrict__ Wq, const float* __restrict__ Wk,
                            const float* __restrict__ Wv, const float* __restrict__ Wo,
                            ushort* __restrict__ Wqb, ushort* __restrict__ Wkb,
                            ushort* __restrict__ Wvb, ushort* __restrict__ Wob) {
  int i = blockIdx.x * blockDim.x + threadIdx.x;
  const int NW = HH*DD*DD;           // 49152
  if (i < NW) { Wqb[i] = f2bf(Wq[i]); Wkb[i] = f2bf(Wk[i]); Wvb[i] = f2bf(Wv[i]); }
  if (i < EE*EE) Wob[i] = f2bf(Wo[i]);
}

// ---------------- QKV projection ----------------
// Q,K out: [B,H,S,D] bf16 (Q pre-scaled by 1/8).  V out: [B,H,D,S] bf16 (transposed).
__global__ __launch_bounds__(256) void proj_qkv(
    const float* __restrict__ q, const float* __restrict__ k, const float* __restrict__ v,
    const ushort* __restrict__ Wqb, const ushort* __restrict__ Wkb, const ushort* __restrict__ Wvb,
    ushort* __restrict__ Qb, ushort* __restrict__ Kb, ushort* __restrict__ Vt) {
  int bid = blockIdx.x;
  int m  = bid / (BB*HH*(SS/64));
  int r  = bid % (BB*HH*(SS/64));
  int bh = r / (SS/64);
  int st = r % (SS/64);
  int b = bh / HH, h = bh % HH;

  const float*  x = (m==0 ? q : (m==1 ? k : v)) + ((size_t)(b*SS + st*64))*EE + h*DD;
  const ushort* W = (m==0 ? Wqb : (m==1 ? Wkb : Wvb)) + h*DD*DD;

  int tid = threadIdx.x;
  int w = tid >> 6, l = tid & 63;
  int lr = l & 15, lg = l >> 4;

  bf16x8 a[2];
  const float* xr = x + (size_t)(w*16 + lr)*EE;
#pragma unroll
  for (int ks = 0; ks < 2; ++ks) {
    f32x4 t0 = *(const f32x4*)(xr + ks*32 + lg*8);
    f32x4 t1 = *(const f32x4*)(xr + ks*32 + lg*8 + 4);
    bf16x8 av;
#pragma unroll
    for (int j = 0; j < 4; ++j) { av[j] = (short)f2bf(t0[j]); av[4+j] = (short)f2bf(t1[j]); }
    a[ks] = av;
  }

  f32x4 acc[4] = {};
#pragma unroll
  for (int f = 0; f < 4; ++f) {
    bf16x8 b0 = *(const bf16x8*)(W + (f*16 + lr)*DD + lg*8);
    bf16x8 b1 = *(const bf16x8*)(W + (f*16 + lr)*DD + 32 + lg*8);
    acc[f] = __builtin_amdgcn_mfma_f32_16x16x32_bf16(a[0], b0, acc[f], 0, 0, 0);
    acc[f] = __builtin_amdgcn_mfma_f32_16x16x32_bf16(a[1], b1, acc[f], 0, 0, 0);
  }

  float qscale = (m == 0) ? 0.125f : 1.0f;
#pragma unroll
  for (int f = 0; f < 4; ++f) {
#pragma unroll
    for (int j = 0; j < 4; ++j) {
      int srow = st*64 + w*16 + lg*4 + j;
      int col  = f*16 + lr;
      ushort val = f2bf(acc[f][j] * qscale);
      if (m == 2)      Vt[((size_t)bh*DD + col)*SS + srow] = val;
      else if (m == 0) Qb[((size_t)bh*SS + srow)*DD + col] = val;
      else             Kb[((size_t)bh*SS + srow)*DD + col] = val;
    }
  }
}

// ---------------- flash attention (swapped-QK, in-register softmax) ----------------
// Block: one (b,h,qtile64). 4 waves x 16 q-rows. K,V double-buffered in LDS.
// K LDS layout: MFMA-fragment-order granules [ks][f][lane]*16B  -> 0-conflict b128 reads.
// V LDS layout: [d][k] row-major 128B rows, XOR-16B swizzle; inverse swizzle on global src.
// PV consumes k in sigma-permuted order so P B-fragments are lane-local (no P in LDS).
__global__ __launch_bounds__(256) void attn_fwd(
    const ushort* __restrict__ Qb, const ushort* __restrict__ Kb,
    const ushort* __restrict__ Vt, ushort* __restrict__ attn) {
  __shared__ uint4 ldsq[2048];     // 32 KiB: 2 buffers x (K 8KB + V 8KB)
  char* ldsb = (char*)ldsq;

  int bid = blockIdx.x;
  int bh = bid >> 4;
  int qt = bid & 15;
  int b = bh / HH, h = bh % HH;
  int tid = threadIdx.x, w = tid >> 6, l = tid & 63;
  int lr = l & 15, lg = l >> 4;

  // Q as MFMA B-operand fragments (col = q = lr, k-dim = d)
  const ushort* Qp = Qb + ((size_t)bh*SS + qt*64 + w*16 + lr)*DD;
  bf16x8 bq0 = *(const bf16x8*)(Qp + lg*8);
  bf16x8 bq1 = *(const bf16x8*)(Qp + 32 + lg*8);

  const ushort* Kbh = Kb + (size_t)bh*SS*DD;
  const ushort* Vbh = Vt + (size_t)bh*DD*SS;

  // V staging source indices (inverse-swizzled)
  int rV = tid >> 3;                                  // d row 0..31 (+32 for issue 1)
  int cVsw = (((tid & 7) * 16) ^ ((rV & 7) << 4)) >> 1;  // element offset in tile row

  float m_run = -1e30f, l_run = 0.f;
  f32x4 o[4] = {};

#define STAGE(bufidx, kt) do {                                                   \
    char* LK_ = ldsb + (bufidx)*16384;                                           \
    char* LV_ = LK_ + 8192;                                                      \
    const ushort* ksrc = Kbh + ((size_t)((kt)*64 + w*16 + lr))*DD;               \
    const ushort* vsrc = Vbh + (kt)*64 + cVsw;                                   \
    gl2lds(ksrc + lg*8,               LK_ + tid*16);                             \
    gl2lds(ksrc + 32 + lg*8,          LK_ + 4096 + tid*16);                      \
    gl2lds(vsrc + (size_t)rV*SS,      LV_ + tid*16);                             \
    gl2lds(vsrc + (size_t)(rV+32)*SS, LV_ + 4096 + tid*16);                      \
  } while (0)

#define COMPUTE(bufidx) do {                                                     \
    const char* LK_ = ldsb + (bufidx)*16384;                                     \
    const char* LV_ = LK_ + 8192;                                                \
    f32x4 st[4] = {};                                                            \
    _Pragma("unroll")                                                            \
    for (int f = 0; f < 4; ++f) {                                                \
      bf16x8 k0 = *(const bf16x8*)(LK_ + f*1024 + l*16);                         \
      bf16x8 k1 = *(const bf16x8*)(LK_ + 4096 + f*1024 + l*16);                  \
      st[f] = __builtin_amdgcn_mfma_f32_16x16x32_bf16(k0, bq0, st[f], 0, 0, 0);  \
      st[f] = __builtin_amdgcn_mfma_f32_16x16x32_bf16(k1, bq1, st[f], 0, 0, 0);  \
    }                                                                            \
    float m0 = fmaxf(fmaxf(st[0][0], st[0][1]), fmaxf(st[0][2], st[0][3]));      \
    float m1 = fmaxf(fmaxf(st[1][0], st[1][1]), fmaxf(st[1][2], st[1][3]));      \
    float m2 = fmaxf(fmaxf(st[2][0], st[2][1]), fmaxf(st[2][2], st[2][3]));      \
    float m3 = fmaxf(fmaxf(st[3][0], st[3][1]), fmaxf(st[3][2], st[3][3]));      \
    float pm = fmaxf(fmaxf(m0, m1), fmaxf(m2, m3));                              \
    pm = fmaxf(pm, __shfl_xor(pm, 16, 64));                                      \
    pm = fmaxf(pm, __shfl_xor(pm, 32, 64));                                      \
    if (!__all(pm <= m_run + 8.f)) {                                             \
      float mn = fmaxf(m_run, pm);                                               \
      float sc = __expf(m_run - mn);                                             \
      m_run = mn; l_run *= sc;                                                   \
      _Pragma("unroll")                                                          \
      for (int f = 0; f < 4; ++f) o[f] *= sc;                                    \
    }                                                                            \
    float rs = 0.f;                                                              \
    _Pragma("unroll")                                                            \
    for (int f = 0; f < 4; ++f) {                                                \
      _Pragma("unroll")                                                          \
      for (int j = 0; j < 4; ++j) {                                              \
        float pv = __expf(st[f][j] - m_run);                                     \
        st[f][j] = pv; rs += pv;                                                 \
      }                                                                          \
    }                                                                            \
    rs += __shfl_xor(rs, 16, 64);                                                \
    rs += __shfl_xor(rs, 32, 64);                                                \
    l_run += rs;                                                                 \
    union { bf16x8 v; unsigned u[4]; } pb0, pb1;                                 \
    pb0.u[0] = pk2(st[0][0], st[0][1]); pb0.u[1] = pk2(st[0][2], st[0][3]);      \
    pb0.u[2] = pk2(st[1][0], st[1][1]); pb0.u[3] = pk2(st[1][2], st[1][3]);      \
    pb1.u[0] = pk2(st[2][0], st[2][1]); pb1.u[1] = pk2(st[2][2], st[2][3]);      \
    pb1.u[2] = pk2(st[3][0], st[3][1]); pb1.u[3] = pk2(st[3][2], st[3][3]);      \
    _Pragma("unroll")                                                            \
    for (int f = 0; f < 4; ++f) {                                                \
      int rb = (f*16 + lr)*128;                                                  \
      int sw = (lr & 7) << 4;                                                    \
      bf16x4 c0 = *(const bf16x4*)(LV_ + rb + ((lg*8) ^ sw));                    \
      bf16x4 c1 = *(const bf16x4*)(LV_ + rb + ((32 + lg*8) ^ sw));               \
      o[f] = __builtin_amdgcn_mfma_f32_16x16x32_bf16(cat8(c0, c1), pb0.v, o[f], 0, 0, 0); \
      bf16x4 c2 = *(const bf16x4*)(LV_ + rb + ((64 + lg*8) ^ sw));               \
      bf16x4 c3 = *(const bf16x4*)(LV_ + rb + ((96 + lg*8) ^ sw));               \
      o[f] = __builtin_amdgcn_mfma_f32_16x16x32_bf16(cat8(c2, c3), pb1.v, o[f], 0, 0, 0); \
    }                                                                            \
  } while (0)

  STAGE(0, 0);
  __syncthreads();
  for (int kt = 0; kt < 16; kt += 2) {
    STAGE(1, kt + 1);
    COMPUTE(0);
    __syncthreads();
    if (kt < 14) STAGE(0, kt + 2);
    COMPUTE(1);
    __syncthreads();
  }
#undef STAGE
#undef COMPUTE

  // epilogue: O^T[d][q]: lane q=lr holds d = f*16 + lg*4 + {0..3}
  float inv = 1.0f / l_run;
  ushort* orow = attn + ((size_t)(b*SS + qt*64 + w*16 + lr))*EE + h*DD;
#pragma unroll
  for (int f = 0; f < 4; ++f) {
    ushort4 pkd;
    pkd.x = f2bf(o[f][0] * inv);
    pkd.y = f2bf(o[f][1] * inv);
    pkd.z = f2bf(o[f][2] * inv);
    pkd.w = f2bf(o[f][3] * inv);
    *(ushort4*)(orow + f*16 + lg*4) = pkd;
  }
}

// ---------------- output projection ----------------
__global__ __launch_bounds__(256) void out_proj(
    const ushort* __restrict__ attn, const ushort* __restrict__ Wob,
    const float* __restrict__ bo, float* __restrict__ out) {
  int bid = blockIdx.x;
  int mt = bid / (EE/64);
  int nt = bid % (EE/64);
  int tid = threadIdx.x, w = tid >> 6, l = tid & 63;
  int lr = l & 15, lg = l >> 4;

  const ushort* ar = attn + ((size_t)(mt*64 + w*16 + lr))*EE;
  f32x4 acc[4] = {};
  for (int ks = 0; ks < EE/32; ++ks) {
    bf16x8 a = *(const bf16x8*)(ar + ks*32 + lg*8);
#pragma unroll
    for (int f = 0; f < 4; ++f) {
      bf16x8 bb = *(const bf16x8*)(Wob + (size_t)(nt*64 + f*16 + lr)*EE + ks*32 + lg*8);
      acc[f] = __builtin_amdgcn_mfma_f32_16x16x32_bf16(a, bb, acc[f], 0, 0, 0);
    }
  }
#pragma unroll
  for (int f = 0; f < 4; ++f) {
    int col = nt*64 + f*16 + lr;
    float bias = bo[col];
#pragma unroll
    for (int j = 0; j < 4; ++j) {
      int row = mt*64 + w*16 + lg*4 + j;
      out[(size_t)row*EE + col] = acc[f][j] + bias;
    }
  }
}

extern "C" void kernel_launch(void* const* d_in, const int* in_sizes, int n_in,
                              void* d_out, int out_size, void* d_ws, size_t ws_size,
                              hipStream_t stream) {
  (void)in_sizes; (void)n_in; (void)out_size; (void)ws_size;
  const float* q  = (const float*)d_in[0];
  const float* k  = (const float*)d_in[1];
  const float* v  = (const float*)d_in[2];
  const float* Wq = (const float*)d_in[3];
  const float* Wk = (const float*)d_in[4];
  const float* Wv = (const float*)d_in[5];
  const float* Wo = (const float*)d_in[6];
  const float* bo = (const float*)d_in[7];
  float* out = (float*)d_out;

  char* ws = (char*)d_ws;
  const size_t SZ = (size_t)BB*HH*SS*DD*2;     // 12582912 bytes each
  ushort* Qb   = (ushort*)(ws);
  ushort* Kb   = (ushort*)(ws + SZ);
  ushort* Vt   = (ushort*)(ws + 2*SZ);
  ushort* attn = (ushort*)(ws + 3*SZ);
  ushort* Wqb  = (ushort*)(ws + 4*SZ);
  ushort* Wkb  = (ushort*)(ws + 4*SZ +   98304);
  ushort* Wvb  = (ushort*)(ws + 4*SZ + 2*98304);
  ushort* Wob  = (ushort*)(ws + 4*SZ + 3*98304);

  cvt_weights<<<(EE*EE + 255)/256, 256, 0, stream>>>(Wq, Wk, Wv, Wo, Wqb, Wkb, Wvb, Wob);
  proj_qkv<<<3*BB*HH*(SS/64), 256, 0, stream>>>(q, k, v, Wqb, Wkb, Wvb, Qb, Kb, Vt);
  attn_fwd<<<BB*HH*(SS/64), 256, 0, stream>>>(Qb, Kb, Vt, attn);
  out_proj<<<(NT/64)*(EE/64), 256, 0, stream>>>(attn, Wob, bo, out);
}

// Round 3
// 119.008 us; speedup vs baseline: 2.7866x; 1.5263x over previous
//
#include <hip/hip_runtime.h>
#include <hip/hip_bf16.h>

#define BB 8
#define SS 1024
#define EE 768
#define HH 12
#define DD 64
#define NT (BB*SS)

typedef __attribute__((ext_vector_type(8))) short bf16x8;
typedef __attribute__((ext_vector_type(4))) short bf16x4;
typedef __attribute__((ext_vector_type(4))) float f32x4;

__device__ __forceinline__ ushort f2bf(float f) {
  union { float f; unsigned u; } x; x.f = f;
  unsigned r = x.u + 0x7fffu + ((x.u >> 16) & 1u);
  return (ushort)(r >> 16);
}

// pack two floats to bf16 pair (simple round-half-up)
__device__ __forceinline__ unsigned pk2(float a, float b) {
  union { float f; unsigned u; } A, B; A.f = a; B.f = b;
  return ((A.u + 0x8000u) >> 16) | ((B.u + 0x8000u) & 0xffff0000u);
}

__device__ __forceinline__ bf16x8 cat8(bf16x4 a, bf16x4 b) {
  bf16x8 r;
  r[0]=a[0]; r[1]=a[1]; r[2]=a[2]; r[3]=a[3];
  r[4]=b[0]; r[5]=b[1]; r[6]=b[2]; r[7]=b[3];
  return r;
}

__device__ __forceinline__ void gl2lds(const void* g, void* l) {
  __builtin_amdgcn_global_load_lds(
      (const __attribute__((address_space(1))) unsigned int*)g,
      (__attribute__((address_space(3))) unsigned int*)l, 16, 0, 0);
}

// ---------------- weight conversion ----------------
__global__ void cvt_weights(const float* __restrict__ Wq, const float* __restrict__ Wk,
                            const float* __restrict__ Wv, const float* __restrict__ Wo,
                            ushort* __restrict__ Wqb, ushort* __restrict__ Wkb,
                            ushort* __restrict__ Wvb, ushort* __restrict__ Wob) {
  int i = blockIdx.x * blockDim.x + threadIdx.x;
  const int NW = HH*DD*DD;           // 49152
  if (i < NW) { Wqb[i] = f2bf(Wq[i]); Wkb[i] = f2bf(Wk[i]); Wvb[i] = f2bf(Wv[i]); }
  if (i < EE*EE) Wob[i] = f2bf(Wo[i]);
}

// ---------------- QKV projection ----------------
// Q,K out: [B,H,S,D] bf16 (Q pre-scaled by 1/8).  V out: [B,H,D,S] bf16 (transposed).
__global__ __launch_bounds__(256) void proj_qkv(
    const float* __restrict__ q, const float* __restrict__ k, const float* __restrict__ v,
    const ushort* __restrict__ Wqb, const ushort* __restrict__ Wkb, const ushort* __restrict__ Wvb,
    ushort* __restrict__ Qb, ushort* __restrict__ Kb, ushort* __restrict__ Vt) {
  int bid = blockIdx.x;
  int m  = bid / (BB*HH*(SS/64));
  int r  = bid % (BB*HH*(SS/64));
  int bh = r / (SS/64);
  int st = r % (SS/64);
  int b = bh / HH, h = bh % HH;

  const float*  x = (m==0 ? q : (m==1 ? k : v)) + ((size_t)(b*SS + st*64))*EE + h*DD;
  const ushort* W = (m==0 ? Wqb : (m==1 ? Wkb : Wvb)) + h*DD*DD;

  int tid = threadIdx.x;
  int w = tid >> 6, l = tid & 63;
  int lr = l & 15, lg = l >> 4;

  bf16x8 a[2];
  const float* xr = x + (size_t)(w*16 + lr)*EE;
#pragma unroll
  for (int ks = 0; ks < 2; ++ks) {
    f32x4 t0 = *(const f32x4*)(xr + ks*32 + lg*8);
    f32x4 t1 = *(const f32x4*)(xr + ks*32 + lg*8 + 4);
    bf16x8 av;
#pragma unroll
    for (int j = 0; j < 4; ++j) { av[j] = (short)f2bf(t0[j]); av[4+j] = (short)f2bf(t1[j]); }
    a[ks] = av;
  }

  f32x4 acc[4] = {};
#pragma unroll
  for (int f = 0; f < 4; ++f) {
    bf16x8 b0 = *(const bf16x8*)(W + (f*16 + lr)*DD + lg*8);
    bf16x8 b1 = *(const bf16x8*)(W + (f*16 + lr)*DD + 32 + lg*8);
    acc[f] = __builtin_amdgcn_mfma_f32_16x16x32_bf16(a[0], b0, acc[f], 0, 0, 0);
    acc[f] = __builtin_amdgcn_mfma_f32_16x16x32_bf16(a[1], b1, acc[f], 0, 0, 0);
  }

  float qscale = (m == 0) ? 0.125f : 1.0f;
#pragma unroll
  for (int f = 0; f < 4; ++f) {
#pragma unroll
    for (int j = 0; j < 4; ++j) {
      int srow = st*64 + w*16 + lg*4 + j;
      int col  = f*16 + lr;
      ushort val = f2bf(acc[f][j] * qscale);
      if (m == 2)      Vt[((size_t)bh*DD + col)*SS + srow] = val;
      else if (m == 0) Qb[((size_t)bh*SS + srow)*DD + col] = val;
      else             Kb[((size_t)bh*SS + srow)*DD + col] = val;
    }
  }
}

// ---------------- flash attention (swapped-QK, in-register softmax) ----------------
__global__ __launch_bounds__(256) void attn_fwd(
    const ushort* __restrict__ Qb, const ushort* __restrict__ Kb,
    const ushort* __restrict__ Vt, ushort* __restrict__ attn) {
  __shared__ uint4 ldsq[2048];     // 32 KiB: 2 buffers x (K 8KB + V 8KB)
  char* ldsb = (char*)ldsq;

  int bid = blockIdx.x;
  int bh = bid >> 4;
  int qt = bid & 15;
  int b = bh / HH, h = bh % HH;
  int tid = threadIdx.x, w = tid >> 6, l = tid & 63;
  int lr = l & 15, lg = l >> 4;

  // Q as MFMA B-operand fragments (col = q = lr, k-dim = d)
  const ushort* Qp = Qb + ((size_t)bh*SS + qt*64 + w*16 + lr)*DD;
  bf16x8 bq0 = *(const bf16x8*)(Qp + lg*8);
  bf16x8 bq1 = *(const bf16x8*)(Qp + 32 + lg*8);

  const ushort* Kbh = Kb + (size_t)bh*SS*DD;
  const ushort* Vbh = Vt + (size_t)bh*DD*SS;

  // V staging source indices (inverse-swizzled)
  int rV = tid >> 3;                                  // d row 0..31 (+32 for issue 1)
  int cVsw = (((tid & 7) * 16) ^ ((rV & 7) << 4)) >> 1;  // element offset in tile row

  float m_run = -1e30f, l_run = 0.f;
  f32x4 o[4] = {};

#define STAGE(bufidx, kt) do {                                                   \
    char* LK_ = ldsb + (bufidx)*16384;                                           \
    char* LV_ = LK_ + 8192;                                                      \
    const ushort* ksrc = Kbh + ((size_t)((kt)*64 + w*16 + lr))*DD;               \
    const ushort* vsrc = Vbh + (kt)*64 + cVsw;                                   \
    gl2lds(ksrc + lg*8,               LK_ + tid*16);                             \
    gl2lds(ksrc + 32 + lg*8,          LK_ + 4096 + tid*16);                      \
    gl2lds(vsrc + (size_t)rV*SS,      LV_ + tid*16);                             \
    gl2lds(vsrc + (size_t)(rV+32)*SS, LV_ + 4096 + tid*16);                      \
  } while (0)

#define COMPUTE(bufidx) do {                                                     \
    const char* LK_ = ldsb + (bufidx)*16384;                                     \
    const char* LV_ = LK_ + 8192;                                                \
    f32x4 st[4] = {};                                                            \
    _Pragma("unroll")                                                            \
    for (int f = 0; f < 4; ++f) {                                                \
      bf16x8 k0 = *(const bf16x8*)(LK_ + f*1024 + l*16);                         \
      bf16x8 k1 = *(const bf16x8*)(LK_ + 4096 + f*1024 + l*16);                  \
      st[f] = __builtin_amdgcn_mfma_f32_16x16x32_bf16(k0, bq0, st[f], 0, 0, 0);  \
      st[f] = __builtin_amdgcn_mfma_f32_16x16x32_bf16(k1, bq1, st[f], 0, 0, 0);  \
    }                                                                            \
    float m0 = fmaxf(fmaxf(st[0][0], st[0][1]), fmaxf(st[0][2], st[0][3]));      \
    float m1 = fmaxf(fmaxf(st[1][0], st[1][1]), fmaxf(st[1][2], st[1][3]));      \
    float m2 = fmaxf(fmaxf(st[2][0], st[2][1]), fmaxf(st[2][2], st[2][3]));      \
    float m3 = fmaxf(fmaxf(st[3][0], st[3][1]), fmaxf(st[3][2], st[3][3]));      \
    float pm = fmaxf(fmaxf(m0, m1), fmaxf(m2, m3));                              \
    pm = fmaxf(pm, __shfl_xor(pm, 16, 64));                                      \
    pm = fmaxf(pm, __shfl_xor(pm, 32, 64));                                      \
    if (!__all(pm <= m_run + 8.f)) {                                             \
      float mn = fmaxf(m_run, pm);                                               \
      float sc = __expf(m_run - mn);                                             \
      m_run = mn; l_run *= sc;                                                   \
      _Pragma("unroll")                                                          \
      for (int f = 0; f < 4; ++f) o[f] *= sc;                                    \
    }                                                                            \
    float rs = 0.f;                                                              \
    _Pragma("unroll")                                                            \
    for (int f = 0; f < 4; ++f) {                                                \
      _Pragma("unroll")                                                          \
      for (int j = 0; j < 4; ++j) {                                              \
        float pv = __expf(st[f][j] - m_run);                                     \
        st[f][j] = pv; rs += pv;                                                 \
      }                                                                          \
    }                                                                            \
    rs += __shfl_xor(rs, 16, 64);                                                \
    rs += __shfl_xor(rs, 32, 64);                                                \
    l_run += rs;                                                                 \
    union { bf16x8 v; unsigned u[4]; } pb0, pb1;                                 \
    pb0.u[0] = pk2(st[0][0], st[0][1]); pb0.u[1] = pk2(st[0][2], st[0][3]);      \
    pb0.u[2] = pk2(st[1][0], st[1][1]); pb0.u[3] = pk2(st[1][2], st[1][3]);      \
    pb1.u[0] = pk2(st[2][0], st[2][1]); pb1.u[1] = pk2(st[2][2], st[2][3]);      \
    pb1.u[2] = pk2(st[3][0], st[3][1]); pb1.u[3] = pk2(st[3][2], st[3][3]);      \
    _Pragma("unroll")                                                            \
    for (int f = 0; f < 4; ++f) {                                                \
      int rb = (f*16 + lr)*128;                                                  \
      int sw = (lr & 7) << 4;                                                    \
      bf16x4 c0 = *(const bf16x4*)(LV_ + rb + ((lg*8) ^ sw));                    \
      bf16x4 c1 = *(const bf16x4*)(LV_ + rb + ((32 + lg*8) ^ sw));               \
      o[f] = __builtin_amdgcn_mfma_f32_16x16x32_bf16(cat8(c0, c1), pb0.v, o[f], 0, 0, 0); \
      bf16x4 c2 = *(const bf16x4*)(LV_ + rb + ((64 + lg*8) ^ sw));               \
      bf16x4 c3 = *(const bf16x4*)(LV_ + rb + ((96 + lg*8) ^ sw));               \
      o[f] = __builtin_amdgcn_mfma_f32_16x16x32_bf16(cat8(c2, c3), pb1.v, o[f], 0, 0, 0); \
    }                                                                            \
  } while (0)

  STAGE(0, 0);
  __syncthreads();
  for (int kt = 0; kt < 16; kt += 2) {
    STAGE(1, kt + 1);
    COMPUTE(0);
    __syncthreads();
    if (kt < 14) STAGE(0, kt + 2);
    COMPUTE(1);
    __syncthreads();
  }
#undef STAGE
#undef COMPUTE

  // epilogue: O^T[d][q]: lane q=lr holds d = f*16 + lg*4 + {0..3}
  float inv = 1.0f / l_run;
  ushort* orow = attn + ((size_t)(b*SS + qt*64 + w*16 + lr))*EE + h*DD;
#pragma unroll
  for (int f = 0; f < 4; ++f) {
    ushort4 pkd;
    pkd.x = f2bf(o[f][0] * inv);
    pkd.y = f2bf(o[f][1] * inv);
    pkd.z = f2bf(o[f][2] * inv);
    pkd.w = f2bf(o[f][3] * inv);
    *(ushort4*)(orow + f*16 + lg*4) = pkd;
  }
}

// ---------------- output projection (LDS-staged, double-buffered MFMA GEMM) ----------------
// BM=64, BN=128, BK=64. Grid 128x6=768 blocks (3/CU). 4 waves; wave w owns n-cols w*32..w*32+31.
// A-tile [64][64] and B-tile [128][64] both row-major 128B rows, XOR-16B swizzle
// (inverse swizzle applied on global source; gl2lds dest is linear per rule #21).
__global__ __launch_bounds__(256) void out_proj(
    const ushort* __restrict__ attn, const ushort* __restrict__ Wob,
    const float* __restrict__ bo, float* __restrict__ out) {
  __shared__ uint4 ldsq[3072];   // 48 KiB: 2 buffers x (A 8KB + B 16KB)
  char* ldsb = (char*)ldsq;

  int bid = blockIdx.x;
  int mt = bid / (EE/128);       // 0..127
  int nt = bid % (EE/128);       // 0..5
  int tid = threadIdx.x, w = tid >> 6, l = tid & 63;
  int lr = l & 15, lg = l >> 4;

  // staging source helpers: thread t, issue i covers tile row r = i*32 + (t>>3),
  // dest col-byte (t&7)*16; source col-byte = dest ^ ((r&7)<<4)
  int rS = tid >> 3;                       // 0..31
  int cSw = (((tid & 7) * 16) ^ ((rS & 7) << 4)) >> 1;   // element col in 64-wide tile

  const ushort* Abase = attn + ((size_t)mt*64)*EE;
  const ushort* Bbase = Wob + ((size_t)nt*128)*EE;

#define OSTAGE(bufidx, kt) do {                                                  \
    char* LA_ = ldsb + (bufidx)*24576;                                           \
    char* LB_ = LA_ + 8192;                                                      \
    const ushort* asrc = Abase + (kt)*64 + cSw;                                  \
    const ushort* bsrc = Bbase + (kt)*64 + cSw;                                  \
    gl2lds(asrc + (size_t)rS*EE,        LA_ + tid*16);                           \
    gl2lds(asrc + (size_t)(rS+32)*EE,   LA_ + 4096 + tid*16);                    \
    gl2lds(bsrc + (size_t)rS*EE,        LB_ + tid*16);                           \
    gl2lds(bsrc + (size_t)(rS+32)*EE,   LB_ + 4096 + tid*16);                    \
    gl2lds(bsrc + (size_t)(rS+64)*EE,   LB_ + 8192 + tid*16);                    \
    gl2lds(bsrc + (size_t)(rS+96)*EE,   LB_ + 12288 + tid*16);                   \
  } while (0)

  f32x4 acc[4][2] = {};

#define OCOMPUTE(bufidx) do {                                                    \
    const char* LA_ = ldsb + (bufidx)*24576;                                     \
    const char* LB_ = LA_ + 8192;                                                \
    bf16x8 af[4][2], bf[2][2];                                                   \
    _Pragma("unroll")                                                            \
    for (int f = 0; f < 4; ++f) {                                                \
      int row = f*16 + lr; int sw = (row & 7) << 4;                              \
      af[f][0] = *(const bf16x8*)(LA_ + row*128 + ((lg*16) ^ sw));               \
      af[f][1] = *(const bf16x8*)(LA_ + row*128 + ((64 + lg*16) ^ sw));          \
    }                                                                            \
    _Pragma("unroll")                                                            \
    for (int g = 0; g < 2; ++g) {                                                \
      int row = w*32 + g*16 + lr; int sw = (row & 7) << 4;                       \
      bf[g][0] = *(const bf16x8*)(LB_ + row*128 + ((lg*16) ^ sw));               \
      bf[g][1] = *(const bf16x8*)(LB_ + row*128 + ((64 + lg*16) ^ sw));          \
    }                                                                            \
    _Pragma("unroll")                                                            \
    for (int f = 0; f < 4; ++f) {                                                \
      _Pragma("unroll")                                                          \
      for (int g = 0; g < 2; ++g) {                                              \
        acc[f][g] = __builtin_amdgcn_mfma_f32_16x16x32_bf16(af[f][0], bf[g][0], acc[f][g], 0, 0, 0); \
        acc[f][g] = __builtin_amdgcn_mfma_f32_16x16x32_bf16(af[f][1], bf[g][1], acc[f][g], 0, 0, 0); \
      }                                                                          \
    }                                                                            \
  } while (0)

  OSTAGE(0, 0);
  __syncthreads();
  for (int kt = 0; kt < EE/64; ++kt) {
    if (kt < EE/64 - 1) OSTAGE((kt + 1) & 1, kt + 1);
    OCOMPUTE(kt & 1);
    __syncthreads();
  }
#undef OSTAGE
#undef OCOMPUTE

  // epilogue: out[m][n] fp32 + bias
#pragma unroll
  for (int g = 0; g < 2; ++g) {
    int col = nt*128 + w*32 + g*16 + lr;
    float bias = bo[col];
#pragma unroll
    for (int f = 0; f < 4; ++f) {
#pragma unroll
      for (int j = 0; j < 4; ++j) {
        int row = mt*64 + f*16 + lg*4 + j;
        out[(size_t)row*EE + col] = acc[f][g][j] + bias;
      }
    }
  }
}

extern "C" void kernel_launch(void* const* d_in, const int* in_sizes, int n_in,
                              void* d_out, int out_size, void* d_ws, size_t ws_size,
                              hipStream_t stream) {
  (void)in_sizes; (void)n_in; (void)out_size; (void)ws_size;
  const float* q  = (const float*)d_in[0];
  const float* k  = (const float*)d_in[1];
  const float* v  = (const float*)d_in[2];
  const float* Wq = (const float*)d_in[3];
  const float* Wk = (const float*)d_in[4];
  const float* Wv = (const float*)d_in[5];
  const float* Wo = (const float*)d_in[6];
  const float* bo = (const float*)d_in[7];
  float* out = (float*)d_out;

  char* ws = (char*)d_ws;
  const size_t SZ = (size_t)BB*HH*SS*DD*2;     // 12582912 bytes each
  ushort* Qb   = (ushort*)(ws);
  ushort* Kb   = (ushort*)(ws + SZ);
  ushort* Vt   = (ushort*)(ws + 2*SZ);
  ushort* attn = (ushort*)(ws + 3*SZ);
  ushort* Wqb  = (ushort*)(ws + 4*SZ);
  ushort* Wkb  = (ushort*)(ws + 4*SZ +   98304);
  ushort* Wvb  = (ushort*)(ws + 4*SZ + 2*98304);
  ushort* Wob  = (ushort*)(ws + 4*SZ + 3*98304);

  cvt_weights<<<(EE*EE + 255)/256, 256, 0, stream>>>(Wq, Wk, Wv, Wo, Wqb, Wkb, Wvb, Wob);
  proj_qkv<<<3*BB*HH*(SS/64), 256, 0, stream>>>(q, k, v, Wqb, Wkb, Wvb, Qb, Kb, Vt);
  attn_fwd<<<BB*HH*(SS/64), 256, 0, stream>>>(Qb, Kb, Vt, attn);
  out_proj<<<(NT/64)*(EE/128), 256, 0, stream>>>(attn, Wob, bo, out);
}